// Round 10
// baseline (3731.735 us; speedup 1.0000x reference)
//
#include <hip/hip_runtime.h>
#include <hip/hip_fp16.h>

// GPRPropagation: out = sum_k w_k * (D^-1/2 (A+I) D^-1/2)^k x, k=0..ORDER
// N=100000, F=128, E=1600000, ORDER=10.
//
// R6/R7: pull-gather hits ~4.2 TB/s L3-fill wall; every XCD pulls the whole
// 25.6MB hidden buffer through its 4MB L2. R8 (feature slabs, thread-per-node)
// FAILED: resident set 16MB > 4MB L2 (xd + z_new write-allocate + edge stream
// thrashed the slab) and per-lane 16B gathers destroyed coalescing.
// R9: slabs done right. Only z_old slab (3.2MB) is cacheable; edges/xd loads
// and z_new stores are NONTEMPORAL. Wave = 1 dst node: 8 edge-slots x 8
// feature-lanes -> one 32B edge chunk + 8x 32B z-chunks per instruction,
// shfl_xor slot-reduce. Falsifier: FETCH ~105MB => works; >=250MB => revert.
// (R9 fix: nontemporal_store can't take float2 -> two scalar stores.)

#define F 128
#define SCAN_B 256

__global__ void count_kernel(const int* __restrict__ ei, int E,
                             int* __restrict__ cnt) {
    int e = blockIdx.x * blockDim.x + threadIdx.x;
    if (e < E) {
        int c = ei[(size_t)E + e];   // col = destination
        atomicAdd(&cnt[c], 1);
    }
}

// scan1 + dinv fused
__global__ void scan1_kernel(const int* __restrict__ cnt, int* __restrict__ offs,
                             int* __restrict__ bsums, float* __restrict__ dinv,
                             int N) {
    __shared__ int sm[SCAN_B];
    int i = blockIdx.x * SCAN_B + threadIdx.x;
    int v = (i < N) ? cnt[i] : 0;
    if (i < N) dinv[i] = rsqrtf((float)(v + 1));  // + self loop
    sm[threadIdx.x] = v;
    __syncthreads();
    for (int d = 1; d < SCAN_B; d <<= 1) {
        int t = (threadIdx.x >= d) ? sm[threadIdx.x - d] : 0;
        __syncthreads();
        sm[threadIdx.x] += t;
        __syncthreads();
    }
    if (i < N) offs[i] = sm[threadIdx.x] - v;
    if (threadIdx.x == SCAN_B - 1) bsums[blockIdx.x] = sm[SCAN_B - 1];
}

__global__ void scan2_kernel(int* __restrict__ bsums, int nb) {
    __shared__ int sm[SCAN_B];
    __shared__ int carry;
    if (threadIdx.x == 0) carry = 0;
    __syncthreads();
    for (int base = 0; base < nb; base += SCAN_B) {
        int i = base + threadIdx.x;
        int v = (i < nb) ? bsums[i] : 0;
        sm[threadIdx.x] = v;
        __syncthreads();
        for (int d = 1; d < SCAN_B; d <<= 1) {
            int t = (threadIdx.x >= d) ? sm[threadIdx.x - d] : 0;
            __syncthreads();
            sm[threadIdx.x] += t;
            __syncthreads();
        }
        if (i < nb) bsums[i] = sm[threadIdx.x] - v + carry;
        __syncthreads();
        if (threadIdx.x == 0) carry += sm[SCAN_B - 1];
        __syncthreads();
    }
}

__global__ void scan3_kernel(int* __restrict__ offs, const int* __restrict__ bsums,
                             int* __restrict__ cursor, int N, int E) {
    int i = blockIdx.x * blockDim.x + threadIdx.x;
    if (i < N) {
        int o = offs[i] + bsums[i / SCAN_B];
        offs[i] = o;
        cursor[i] = o;
    }
    if (i == N) offs[N] = E;
}

// 8-group rescan place (R6): group g handles dst range [N*g/8, N*(g+1)/8);
// its CSR slice is contiguous -> XCD-local atomics + full-line writeback.
__global__ void place_kernel(const int* __restrict__ ei, int E,
                             int* __restrict__ cursor, int* __restrict__ edges,
                             int N) {
    const int g = blockIdx.x & 7;
    const int b = blockIdx.x >> 3;
    const int nb = gridDim.x >> 3;
    const int lo = (int)((long long)N * g / 8);
    const int hi = (int)((long long)N * (g + 1) / 8);
    const int stride = nb * blockDim.x;
    for (int e = b * blockDim.x + threadIdx.x; e < E; e += stride) {
        int c = ei[(size_t)E + e];
        if (c < lo || c >= hi) continue;
        int pos = atomicAdd(&cursor[c], 1);
        edges[pos] = ei[e];
    }
}

__device__ __forceinline__ unsigned pk(float a, float b) {
    __half2 h = __floats2half2_rn(a, b);
    return *(unsigned*)&h;
}

// acc.x += f16_lo(raw); acc.y += f16_hi(raw)   (fp32 FMA with inline 1.0)
__device__ __forceinline__ void accmix(float& ax, float& ay, unsigned raw) {
    asm volatile(
        "v_fma_mix_f32 %0, 1.0, %2, %0 op_sel:[0,0,0] op_sel_hi:[0,1,0]\n\t"
        "v_fma_mix_f32 %1, 1.0, %2, %1 op_sel:[0,1,0] op_sel_hi:[0,1,0]"
        : "+v"(ax), "+v"(ay)
        : "v"(raw));
}

// acc.x += w * f16_lo(raw); acc.y += w * f16_hi(raw)
__device__ __forceinline__ void fmamix2(float& ax, float& ay, float w,
                                        unsigned raw) {
    asm volatile(
        "v_fma_mix_f32 %0, %2, %3, %0 op_sel:[0,0,0] op_sel_hi:[0,1,0]\n\t"
        "v_fma_mix_f32 %1, %2, %3, %1 op_sel:[0,1,0] op_sel_hi:[0,1,0]"
        : "+v"(ax), "+v"(ay)
        : "v"(w), "v"(raw));
}

// Seed: xd = fp16(dinv.*x), z = fp16(w[order]*dinv.*x), slab layout
// [g][node][8 u32 (=16 halfs)]. g = blockIdx&7.
__global__ __launch_bounds__(256) void conv_kernel(
    const float* __restrict__ x, const float* __restrict__ dinv,
    unsigned* __restrict__ xd, unsigned* __restrict__ z,
    const float* __restrict__ wts, int order, int N) {
    const int g = blockIdx.x & 7;
    const int c = (blockIdx.x >> 3) * blockDim.x + threadIdx.x;
    if (c >= N) return;
    const float dc = dinv[c];
    const float wl = wts[order] * dc;
    const float2* xr = (const float2*)(x + (size_t)c * F + g * 16);
    size_t off = ((size_t)g * N + c) * 8;
#pragma unroll
    for (int k = 0; k < 8; ++k) {
        float2 v = xr[k];
        xd[off + k] = pk(dc * v.x, dc * v.y);
        z[off + k] = pk(wl * v.x, wl * v.y);
    }
}

// Wave = 1 dst node in slab g. lane = slot*8 + fl: slot = edge position
// (8-way), fl = feature pair (8 half2 = 32B row). Gather is a pure
// unweighted sum of z rows (z = D^-1/2 y absorbs src weights);
// dest scaling applied in epilogue by slot-0 lanes.
__global__ __launch_bounds__(256) void prop_kernel(
    const unsigned* __restrict__ z_old, unsigned* __restrict__ z_new,
    float* __restrict__ out, const unsigned* __restrict__ xd,
    const float* __restrict__ x, const float* __restrict__ dinv,
    const int* __restrict__ offs, const int* __restrict__ edges,
    const float* __restrict__ wts, int j, int last, int N) {
    const int g = blockIdx.x & 7;
    const int lane = threadIdx.x & 63;
    const int slot = lane >> 3;
    const int fl = lane & 7;
    const int c = ((blockIdx.x >> 3) << 2) + (threadIdx.x >> 6);
    if (c >= N) return;
    const unsigned* zs = z_old + (size_t)g * N * 8;  // this XCD's 3.2MB slab

    float ax = 0.0f, ay = 0.0f;
    if (slot == 0) accmix(ax, ay, zs[(size_t)c * 8 + fl]);  // self loop

    const int beg = offs[c];
    const int end = offs[c + 1];
    for (int e = beg + slot; e < end; e += 8) {
        int src = __builtin_nontemporal_load(&edges[e]);
        accmix(ax, ay, zs[(size_t)src * 8 + fl]);
    }

    // reduce over the 8 slots (lane bits 3..5)
    ax += __shfl_xor(ax, 8);
    ay += __shfl_xor(ay, 8);
    ax += __shfl_xor(ax, 16);
    ay += __shfl_xor(ay, 16);
    ax += __shfl_xor(ax, 32);
    ay += __shfl_xor(ay, 32);

    if (slot == 0) {
        const float dc = dinv[c];
        if (last) {
            const float w0 = wts[0];
            float2 xv = ((const float2*)(x + (size_t)c * F + g * 16))[fl];
            float* orow = out + (size_t)c * F + g * 16 + fl * 2;
            __builtin_nontemporal_store(fmaf(dc, ax, w0 * xv.x), orow);
            __builtin_nontemporal_store(fmaf(dc, ay, w0 * xv.y), orow + 1);
        } else {
            const float dc2 = dc * dc;
            const float wj = wts[j];
            size_t off = ((size_t)g * N + c) * 8 + fl;
            unsigned xr = __builtin_nontemporal_load(&xd[off]);
            ax *= dc2;
            ay *= dc2;
            fmamix2(ax, ay, wj, xr);
            __builtin_nontemporal_store(pk(ax, ay), &z_new[off]);
        }
    }
}

extern "C" void kernel_launch(void* const* d_in, const int* in_sizes, int n_in,
                              void* d_out, int out_size, void* d_ws, size_t ws_size,
                              hipStream_t stream) {
    const float* x = (const float*)d_in[0];
    const int* ei = (const int*)d_in[1];
    const float* wts = (const float*)d_in[2];
    float* out = (float*)d_out;

    const int NF = in_sizes[0];
    const int N = NF / F;              // 100000
    const int E = in_sizes[1] / 2;     // 1600000
    const int order = in_sizes[2] - 1; // 10

    char* p = (char*)d_ws;
    auto carve = [&](size_t bytes) {
        void* q = (void*)p;
        p += (bytes + 255) & ~(size_t)255;
        return q;
    };
    int nb = (N + SCAN_B - 1) / SCAN_B;
    int*      cnt   = (int*)carve(sizeof(int) * (size_t)N);  // reused as cursor
    int*      offs  = (int*)carve(sizeof(int) * (size_t)(N + 1));
    int*      bsums = (int*)carve(sizeof(int) * (size_t)nb);
    float*    dinv  = (float*)carve(sizeof(float) * (size_t)N);
    int*      edges = (int*)carve(4ull * (size_t)E);
    unsigned* xd    = (unsigned*)carve(32ull * (size_t)N * 8);
    unsigned* zA    = (unsigned*)carve(32ull * (size_t)N * 8);
    unsigned* zB    = (unsigned*)carve(32ull * (size_t)N * 8);
    int*      cursor = cnt;  // cnt dead after scan1
    (void)ws_size;

    // ---- CSR build + normalization ----
    hipMemsetAsync(cnt, 0, sizeof(int) * (size_t)N, stream);
    count_kernel<<<(E + 255) / 256, 256, 0, stream>>>(ei, E, cnt);
    scan1_kernel<<<nb, SCAN_B, 0, stream>>>(cnt, offs, bsums, dinv, N);
    scan2_kernel<<<1, SCAN_B, 0, stream>>>(bsums, nb);
    scan3_kernel<<<(N + 1 + 255) / 256, 256, 0, stream>>>(offs, bsums, cursor, N, E);
    place_kernel<<<2048, 256, 0, stream>>>(ei, E, cursor, edges, N);

    // ---- seed: xd = dinv.*x, z = w[order]*xd (slab layout) ----
    const int nch = (N + 255) / 256;
    conv_kernel<<<nch * 8, 256, 0, stream>>>(x, dinv, xd, zA, wts, order, N);

    // ---- 10 Horner rounds on z: s = (A+I)z; z' = dinv^2 s + wj xd ----
    const int nodeblk = (N + 3) / 4;
    const unsigned* zin = zA;
    unsigned* zout = zB;
    for (int j = order - 1; j >= 0; --j) {
        int last = (j == 0);
        prop_kernel<<<nodeblk * 8, 256, 0, stream>>>(zin, zout, out, xd, x,
                                                     dinv, offs, edges, wts, j,
                                                     last, N);
        zin = zout;
        zout = (zout == zA) ? zB : zA;
    }
}

// Round 11
// 3051.917 us; speedup vs baseline: 1.2228x; 1.2228x over previous
//
#include <hip/hip_runtime.h>
#include <hip/hip_fp16.h>

// GPRPropagation: out = sum_k w_k * (D^-1/2 (A+I) D^-1/2)^k x, k=0..ORDER
// N=100000, F=128, E=1600000, ORDER=10.
//
// R10 confirmed: feature-sliced slabs ([g][node][16 fp16], blockIdx&7 = XCD
// affinity) make the random gather L2-resident: FETCH 363->55MB. But edge
// loads were NONTEMPORAL -> every edge = ~900cy HBM trip heading a dependent
// edge->z chain => 368us latency-bound. R11: edges via NORMAL cached loads
// (consecutive waves share 128B edge lines; 6.4MB stream + 3.2MB slab fit
// 4MB L2 well enough), slot loop unrolled x2 (two independent chains).
// nt retained ONLY for xd loads + z_new stores (once-per-round traffic).

#define F 128
#define SCAN_B 256

__global__ void count_kernel(const int* __restrict__ ei, int E,
                             int* __restrict__ cnt) {
    int e = blockIdx.x * blockDim.x + threadIdx.x;
    if (e < E) {
        int c = ei[(size_t)E + e];   // col = destination
        atomicAdd(&cnt[c], 1);
    }
}

// scan1 + dinv fused
__global__ void scan1_kernel(const int* __restrict__ cnt, int* __restrict__ offs,
                             int* __restrict__ bsums, float* __restrict__ dinv,
                             int N) {
    __shared__ int sm[SCAN_B];
    int i = blockIdx.x * SCAN_B + threadIdx.x;
    int v = (i < N) ? cnt[i] : 0;
    if (i < N) dinv[i] = rsqrtf((float)(v + 1));  // + self loop
    sm[threadIdx.x] = v;
    __syncthreads();
    for (int d = 1; d < SCAN_B; d <<= 1) {
        int t = (threadIdx.x >= d) ? sm[threadIdx.x - d] : 0;
        __syncthreads();
        sm[threadIdx.x] += t;
        __syncthreads();
    }
    if (i < N) offs[i] = sm[threadIdx.x] - v;
    if (threadIdx.x == SCAN_B - 1) bsums[blockIdx.x] = sm[SCAN_B - 1];
}

__global__ void scan2_kernel(int* __restrict__ bsums, int nb) {
    __shared__ int sm[SCAN_B];
    __shared__ int carry;
    if (threadIdx.x == 0) carry = 0;
    __syncthreads();
    for (int base = 0; base < nb; base += SCAN_B) {
        int i = base + threadIdx.x;
        int v = (i < nb) ? bsums[i] : 0;
        sm[threadIdx.x] = v;
        __syncthreads();
        for (int d = 1; d < SCAN_B; d <<= 1) {
            int t = (threadIdx.x >= d) ? sm[threadIdx.x - d] : 0;
            __syncthreads();
            sm[threadIdx.x] += t;
            __syncthreads();
        }
        if (i < nb) bsums[i] = sm[threadIdx.x] - v + carry;
        __syncthreads();
        if (threadIdx.x == 0) carry += sm[SCAN_B - 1];
        __syncthreads();
    }
}

__global__ void scan3_kernel(int* __restrict__ offs, const int* __restrict__ bsums,
                             int* __restrict__ cursor, int N, int E) {
    int i = blockIdx.x * blockDim.x + threadIdx.x;
    if (i < N) {
        int o = offs[i] + bsums[i / SCAN_B];
        offs[i] = o;
        cursor[i] = o;
    }
    if (i == N) offs[N] = E;
}

// 8-group rescan place (R6): group g handles dst range [N*g/8, N*(g+1)/8);
// its CSR slice is contiguous -> XCD-local atomics + full-line writeback.
__global__ void place_kernel(const int* __restrict__ ei, int E,
                             int* __restrict__ cursor, int* __restrict__ edges,
                             int N) {
    const int g = blockIdx.x & 7;
    const int b = blockIdx.x >> 3;
    const int nb = gridDim.x >> 3;
    const int lo = (int)((long long)N * g / 8);
    const int hi = (int)((long long)N * (g + 1) / 8);
    const int stride = nb * blockDim.x;
    for (int e = b * blockDim.x + threadIdx.x; e < E; e += stride) {
        int c = ei[(size_t)E + e];
        if (c < lo || c >= hi) continue;
        int pos = atomicAdd(&cursor[c], 1);
        edges[pos] = ei[e];
    }
}

__device__ __forceinline__ unsigned pk(float a, float b) {
    __half2 h = __floats2half2_rn(a, b);
    return *(unsigned*)&h;
}

// acc.x += f16_lo(raw); acc.y += f16_hi(raw)   (fp32 FMA with inline 1.0)
__device__ __forceinline__ void accmix(float& ax, float& ay, unsigned raw) {
    asm volatile(
        "v_fma_mix_f32 %0, 1.0, %2, %0 op_sel:[0,0,0] op_sel_hi:[0,1,0]\n\t"
        "v_fma_mix_f32 %1, 1.0, %2, %1 op_sel:[0,1,0] op_sel_hi:[0,1,0]"
        : "+v"(ax), "+v"(ay)
        : "v"(raw));
}

// acc.x += w * f16_lo(raw); acc.y += w * f16_hi(raw)
__device__ __forceinline__ void fmamix2(float& ax, float& ay, float w,
                                        unsigned raw) {
    asm volatile(
        "v_fma_mix_f32 %0, %2, %3, %0 op_sel:[0,0,0] op_sel_hi:[0,1,0]\n\t"
        "v_fma_mix_f32 %1, %2, %3, %1 op_sel:[0,1,0] op_sel_hi:[0,1,0]"
        : "+v"(ax), "+v"(ay)
        : "v"(w), "v"(raw));
}

// Seed: xd = fp16(dinv.*x), z = fp16(w[order]*dinv.*x), slab layout
// [g][node][8 u32 (=16 halfs)]. g = blockIdx&7.
__global__ __launch_bounds__(256) void conv_kernel(
    const float* __restrict__ x, const float* __restrict__ dinv,
    unsigned* __restrict__ xd, unsigned* __restrict__ z,
    const float* __restrict__ wts, int order, int N) {
    const int g = blockIdx.x & 7;
    const int c = (blockIdx.x >> 3) * blockDim.x + threadIdx.x;
    if (c >= N) return;
    const float dc = dinv[c];
    const float wl = wts[order] * dc;
    const float2* xr = (const float2*)(x + (size_t)c * F + g * 16);
    size_t off = ((size_t)g * N + c) * 8;
#pragma unroll
    for (int k = 0; k < 8; ++k) {
        float2 v = xr[k];
        xd[off + k] = pk(dc * v.x, dc * v.y);
        z[off + k] = pk(wl * v.x, wl * v.y);
    }
}

// Wave = 1 dst node in slab g. lane = slot*8 + fl: slot = edge position
// (8-way), fl = feature pair (8 half2 = 32B row). Gather = pure unweighted
// sum of z rows (z = D^-1/2 y absorbs src weights); slot loop unrolled x2
// for two independent edge->z chains in flight.
__global__ __launch_bounds__(256) void prop_kernel(
    const unsigned* __restrict__ z_old, unsigned* __restrict__ z_new,
    float* __restrict__ out, const unsigned* __restrict__ xd,
    const float* __restrict__ x, const float* __restrict__ dinv,
    const int* __restrict__ offs, const int* __restrict__ edges,
    const float* __restrict__ wts, int j, int last, int N) {
    const int g = blockIdx.x & 7;
    const int lane = threadIdx.x & 63;
    const int slot = lane >> 3;
    const int fl = lane & 7;
    const int c = ((blockIdx.x >> 3) << 2) + (threadIdx.x >> 6);
    if (c >= N) return;
    const unsigned* zs = z_old + (size_t)g * N * 8;  // this XCD's 3.2MB slab

    float ax = 0.0f, ay = 0.0f;
    if (slot == 0) accmix(ax, ay, zs[(size_t)c * 8 + fl]);  // self loop

    const int beg = offs[c];
    const int end = offs[c + 1];
    int e = beg + slot;
    for (; e + 8 < end; e += 16) {
        int s0 = edges[e];
        int s1 = edges[e + 8];
        unsigned z0 = zs[(size_t)s0 * 8 + fl];
        unsigned z1 = zs[(size_t)s1 * 8 + fl];
        accmix(ax, ay, z0);
        accmix(ax, ay, z1);
    }
    if (e < end) {
        int s0 = edges[e];
        accmix(ax, ay, zs[(size_t)s0 * 8 + fl]);
    }

    // reduce over the 8 slots (lane bits 3..5)
    ax += __shfl_xor(ax, 8);
    ay += __shfl_xor(ay, 8);
    ax += __shfl_xor(ax, 16);
    ay += __shfl_xor(ay, 16);
    ax += __shfl_xor(ax, 32);
    ay += __shfl_xor(ay, 32);

    if (slot == 0) {
        const float dc = dinv[c];
        if (last) {
            const float w0 = wts[0];
            float2 xv = ((const float2*)(x + (size_t)c * F + g * 16))[fl];
            float* orow = out + (size_t)c * F + g * 16 + fl * 2;
            __builtin_nontemporal_store(fmaf(dc, ax, w0 * xv.x), orow);
            __builtin_nontemporal_store(fmaf(dc, ay, w0 * xv.y), orow + 1);
        } else {
            const float dc2 = dc * dc;
            const float wj = wts[j];
            size_t off = ((size_t)g * N + c) * 8 + fl;
            unsigned xr = __builtin_nontemporal_load(&xd[off]);
            ax *= dc2;
            ay *= dc2;
            fmamix2(ax, ay, wj, xr);
            __builtin_nontemporal_store(pk(ax, ay), &z_new[off]);
        }
    }
}

extern "C" void kernel_launch(void* const* d_in, const int* in_sizes, int n_in,
                              void* d_out, int out_size, void* d_ws, size_t ws_size,
                              hipStream_t stream) {
    const float* x = (const float*)d_in[0];
    const int* ei = (const int*)d_in[1];
    const float* wts = (const float*)d_in[2];
    float* out = (float*)d_out;

    const int NF = in_sizes[0];
    const int N = NF / F;              // 100000
    const int E = in_sizes[1] / 2;     // 1600000
    const int order = in_sizes[2] - 1; // 10

    char* p = (char*)d_ws;
    auto carve = [&](size_t bytes) {
        void* q = (void*)p;
        p += (bytes + 255) & ~(size_t)255;
        return q;
    };
    int nb = (N + SCAN_B - 1) / SCAN_B;
    int*      cnt   = (int*)carve(sizeof(int) * (size_t)N);  // reused as cursor
    int*      offs  = (int*)carve(sizeof(int) * (size_t)(N + 1));
    int*      bsums = (int*)carve(sizeof(int) * (size_t)nb);
    float*    dinv  = (float*)carve(sizeof(float) * (size_t)N);
    int*      edges = (int*)carve(4ull * (size_t)E);
    unsigned* xd    = (unsigned*)carve(32ull * (size_t)N * 8);
    unsigned* zA    = (unsigned*)carve(32ull * (size_t)N * 8);
    unsigned* zB    = (unsigned*)carve(32ull * (size_t)N * 8);
    int*      cursor = cnt;  // cnt dead after scan1
    (void)ws_size;

    // ---- CSR build + normalization ----
    hipMemsetAsync(cnt, 0, sizeof(int) * (size_t)N, stream);
    count_kernel<<<(E + 255) / 256, 256, 0, stream>>>(ei, E, cnt);
    scan1_kernel<<<nb, SCAN_B, 0, stream>>>(cnt, offs, bsums, dinv, N);
    scan2_kernel<<<1, SCAN_B, 0, stream>>>(bsums, nb);
    scan3_kernel<<<(N + 1 + 255) / 256, 256, 0, stream>>>(offs, bsums, cursor, N, E);
    place_kernel<<<2048, 256, 0, stream>>>(ei, E, cursor, edges, N);

    // ---- seed: xd = dinv.*x, z = w[order]*xd (slab layout) ----
    const int nch = (N + 255) / 256;
    conv_kernel<<<nch * 8, 256, 0, stream>>>(x, dinv, xd, zA, wts, order, N);

    // ---- 10 Horner rounds on z: s = (A+I)z; z' = dinv^2 s + wj xd ----
    const int nodeblk = (N + 3) / 4;
    const unsigned* zin = zA;
    unsigned* zout = zB;
    for (int j = order - 1; j >= 0; --j) {
        int last = (j == 0);
        prop_kernel<<<nodeblk * 8, 256, 0, stream>>>(zin, zout, out, xd, x,
                                                     dinv, offs, edges, wts, j,
                                                     last, N);
        zin = zout;
        zout = (zout == zA) ? zB : zA;
    }
}

// Round 12
// 1752.969 us; speedup vs baseline: 2.1288x; 1.7410x over previous
//
#include <hip/hip_runtime.h>
#include <hip/hip_fp16.h>

// GPRPropagation: out = sum_k w_k * (D^-1/2 (A+I) D^-1/2)^k x, k=0..ORDER
// N=100000, F=128, E=1600000, ORDER=10.
//
// Confirmed (R10/R11): feature-sliced slabs [g][node][16 fp16] with
// blockIdx&7 XCD affinity make random gathers L2-resident (FETCH 54MB =
// compulsory floor). R11 was still latency-bound: 800k tiny waves, 1 edge
// per gather instruction, serialized chain. R12: wave = 8 consecutive
// nodes (slot) x 8 feature-lanes (fl). One gather instruction serves 8
// edges (8x32B chunks); no cross-slot reduce; epilogue xd/z_new fully
// coalesced 256B nt ops; unroll-2 over the predicated max-degree loop.

#define F 128
#define SCAN_B 256

__global__ void count_kernel(const int* __restrict__ ei, int E,
                             int* __restrict__ cnt) {
    int e = blockIdx.x * blockDim.x + threadIdx.x;
    if (e < E) {
        int c = ei[(size_t)E + e];   // col = destination
        atomicAdd(&cnt[c], 1);
    }
}

// scan1 + dinv fused
__global__ void scan1_kernel(const int* __restrict__ cnt, int* __restrict__ offs,
                             int* __restrict__ bsums, float* __restrict__ dinv,
                             int N) {
    __shared__ int sm[SCAN_B];
    int i = blockIdx.x * SCAN_B + threadIdx.x;
    int v = (i < N) ? cnt[i] : 0;
    if (i < N) dinv[i] = rsqrtf((float)(v + 1));  // + self loop
    sm[threadIdx.x] = v;
    __syncthreads();
    for (int d = 1; d < SCAN_B; d <<= 1) {
        int t = (threadIdx.x >= d) ? sm[threadIdx.x - d] : 0;
        __syncthreads();
        sm[threadIdx.x] += t;
        __syncthreads();
    }
    if (i < N) offs[i] = sm[threadIdx.x] - v;
    if (threadIdx.x == SCAN_B - 1) bsums[blockIdx.x] = sm[SCAN_B - 1];
}

__global__ void scan2_kernel(int* __restrict__ bsums, int nb) {
    __shared__ int sm[SCAN_B];
    __shared__ int carry;
    if (threadIdx.x == 0) carry = 0;
    __syncthreads();
    for (int base = 0; base < nb; base += SCAN_B) {
        int i = base + threadIdx.x;
        int v = (i < nb) ? bsums[i] : 0;
        sm[threadIdx.x] = v;
        __syncthreads();
        for (int d = 1; d < SCAN_B; d <<= 1) {
            int t = (threadIdx.x >= d) ? sm[threadIdx.x - d] : 0;
            __syncthreads();
            sm[threadIdx.x] += t;
            __syncthreads();
        }
        if (i < nb) bsums[i] = sm[threadIdx.x] - v + carry;
        __syncthreads();
        if (threadIdx.x == 0) carry += sm[SCAN_B - 1];
        __syncthreads();
    }
}

__global__ void scan3_kernel(int* __restrict__ offs, const int* __restrict__ bsums,
                             int* __restrict__ cursor, int N, int E) {
    int i = blockIdx.x * blockDim.x + threadIdx.x;
    if (i < N) {
        int o = offs[i] + bsums[i / SCAN_B];
        offs[i] = o;
        cursor[i] = o;
    }
    if (i == N) offs[N] = E;
}

// 8-group rescan place (R6): group g handles dst range [N*g/8, N*(g+1)/8);
// its CSR slice is contiguous -> XCD-local atomics + full-line writeback.
__global__ void place_kernel(const int* __restrict__ ei, int E,
                             int* __restrict__ cursor, int* __restrict__ edges,
                             int N) {
    const int g = blockIdx.x & 7;
    const int b = blockIdx.x >> 3;
    const int nb = gridDim.x >> 3;
    const int lo = (int)((long long)N * g / 8);
    const int hi = (int)((long long)N * (g + 1) / 8);
    const int stride = nb * blockDim.x;
    for (int e = b * blockDim.x + threadIdx.x; e < E; e += stride) {
        int c = ei[(size_t)E + e];
        if (c < lo || c >= hi) continue;
        int pos = atomicAdd(&cursor[c], 1);
        edges[pos] = ei[e];
    }
}

__device__ __forceinline__ unsigned pk(float a, float b) {
    __half2 h = __floats2half2_rn(a, b);
    return *(unsigned*)&h;
}

// acc.x += f16_lo(raw); acc.y += f16_hi(raw)   (fp32 FMA with inline 1.0)
__device__ __forceinline__ void accmix(float& ax, float& ay, unsigned raw) {
    asm volatile(
        "v_fma_mix_f32 %0, 1.0, %2, %0 op_sel:[0,0,0] op_sel_hi:[0,1,0]\n\t"
        "v_fma_mix_f32 %1, 1.0, %2, %1 op_sel:[0,1,0] op_sel_hi:[0,1,0]"
        : "+v"(ax), "+v"(ay)
        : "v"(raw));
}

// acc.x += w * f16_lo(raw); acc.y += w * f16_hi(raw)
__device__ __forceinline__ void fmamix2(float& ax, float& ay, float w,
                                        unsigned raw) {
    asm volatile(
        "v_fma_mix_f32 %0, %2, %3, %0 op_sel:[0,0,0] op_sel_hi:[0,1,0]\n\t"
        "v_fma_mix_f32 %1, %2, %3, %1 op_sel:[0,1,0] op_sel_hi:[0,1,0]"
        : "+v"(ax), "+v"(ay)
        : "v"(w), "v"(raw));
}

// Seed: xd = fp16(dinv.*x), z = fp16(w[order]*dinv.*x), slab layout
// [g][node][8 u32 (=16 halfs)]. g = blockIdx&7.
__global__ __launch_bounds__(256) void conv_kernel(
    const float* __restrict__ x, const float* __restrict__ dinv,
    unsigned* __restrict__ xd, unsigned* __restrict__ z,
    const float* __restrict__ wts, int order, int N) {
    const int g = blockIdx.x & 7;
    const int c = (blockIdx.x >> 3) * blockDim.x + threadIdx.x;
    if (c >= N) return;
    const float dc = dinv[c];
    const float wl = wts[order] * dc;
    const float2* xr = (const float2*)(x + (size_t)c * F + g * 16);
    size_t off = ((size_t)g * N + c) * 8;
#pragma unroll
    for (int k = 0; k < 8; ++k) {
        float2 v = xr[k];
        xd[off + k] = pk(dc * v.x, dc * v.y);
        z[off + k] = pk(wl * v.x, wl * v.y);
    }
}

// Wave = 8 consecutive dst nodes (slot = lane>>3) x 8 feature pairs
// (fl = lane&7). Each slot walks its own node's edge list; one z-gather
// instruction serves 8 edges (8 x 32B chunks from the L2-resident slab).
// Predicated max-degree loop, unroll x2. No cross-lane reduction.
__global__ __launch_bounds__(256) void prop_kernel(
    const unsigned* __restrict__ z_old, unsigned* __restrict__ z_new,
    float* __restrict__ out, const unsigned* __restrict__ xd,
    const float* __restrict__ x, const float* __restrict__ dinv,
    const int* __restrict__ offs, const int* __restrict__ edges,
    const float* __restrict__ wts, int j, int last, int N, int E) {
    const int g = blockIdx.x & 7;
    const int lane = threadIdx.x & 63;
    const int slot = lane >> 3;
    const int fl = lane & 7;
    const int c = (((blockIdx.x >> 3) << 2) + (threadIdx.x >> 6)) * 8 + slot;
    const bool act = (c < N);
    const unsigned* zs = z_old + (size_t)g * N * 8;  // this XCD's 3.2MB slab

    const int beg = act ? offs[c] : 0;
    const int end = act ? offs[c + 1] : 0;

    float ax = 0.0f, ay = 0.0f;
    if (act) accmix(ax, ay, zs[(size_t)c * 8 + fl]);  // self loop

    // wave-uniform trip count = max degree over the 8 slots (lane bits 3..5)
    int m = end - beg;
    m = max(m, __shfl_xor(m, 8));
    m = max(m, __shfl_xor(m, 16));
    m = max(m, __shfl_xor(m, 32));

    int it = 0;
    for (; it + 2 <= m; it += 2) {
        const int e0 = beg + it;
        const int e1 = beg + it + 1;
        unsigned z0 = 0u, z1 = 0u;
        if (e0 < end) {
            int s0 = edges[e0];
            z0 = zs[(size_t)s0 * 8 + fl];
        }
        if (e1 < end) {
            int s1 = edges[e1];
            z1 = zs[(size_t)s1 * 8 + fl];
        }
        accmix(ax, ay, z0);
        accmix(ax, ay, z1);
    }
    if (it < m) {
        const int e0 = beg + it;
        unsigned z0 = 0u;
        if (e0 < end) {
            int s0 = edges[e0];
            z0 = zs[(size_t)s0 * 8 + fl];
        }
        accmix(ax, ay, z0);
    }

    if (act) {
        const float dc = dinv[c];
        if (last) {
            const float w0 = wts[0];
            const float2 xv = ((const float2*)(x + (size_t)c * F + g * 16))[fl];
            float* orow = out + (size_t)c * F + g * 16 + fl * 2;
            __builtin_nontemporal_store(fmaf(dc, ax, w0 * xv.x), orow);
            __builtin_nontemporal_store(fmaf(dc, ay, w0 * xv.y), orow + 1);
        } else {
            const float dc2 = dc * dc;
            const float wj = wts[j];
            size_t off = ((size_t)g * N + c) * 8 + fl;
            unsigned xr = __builtin_nontemporal_load(&xd[off]);
            ax *= dc2;
            ay *= dc2;
            fmamix2(ax, ay, wj, xr);
            __builtin_nontemporal_store(pk(ax, ay), &z_new[off]);
        }
    }
}

extern "C" void kernel_launch(void* const* d_in, const int* in_sizes, int n_in,
                              void* d_out, int out_size, void* d_ws, size_t ws_size,
                              hipStream_t stream) {
    const float* x = (const float*)d_in[0];
    const int* ei = (const int*)d_in[1];
    const float* wts = (const float*)d_in[2];
    float* out = (float*)d_out;

    const int NF = in_sizes[0];
    const int N = NF / F;              // 100000
    const int E = in_sizes[1] / 2;     // 1600000
    const int order = in_sizes[2] - 1; // 10

    char* p = (char*)d_ws;
    auto carve = [&](size_t bytes) {
        void* q = (void*)p;
        p += (bytes + 255) & ~(size_t)255;
        return q;
    };
    int nb = (N + SCAN_B - 1) / SCAN_B;
    int*      cnt   = (int*)carve(sizeof(int) * (size_t)N);  // reused as cursor
    int*      offs  = (int*)carve(sizeof(int) * (size_t)(N + 1));
    int*      bsums = (int*)carve(sizeof(int) * (size_t)nb);
    float*    dinv  = (float*)carve(sizeof(float) * (size_t)N);
    int*      edges = (int*)carve(4ull * (size_t)E);
    unsigned* xd    = (unsigned*)carve(32ull * (size_t)N * 8);
    unsigned* zA    = (unsigned*)carve(32ull * (size_t)N * 8);
    unsigned* zB    = (unsigned*)carve(32ull * (size_t)N * 8);
    int*      cursor = cnt;  // cnt dead after scan1
    (void)ws_size;

    // ---- CSR build + normalization ----
    hipMemsetAsync(cnt, 0, sizeof(int) * (size_t)N, stream);
    count_kernel<<<(E + 255) / 256, 256, 0, stream>>>(ei, E, cnt);
    scan1_kernel<<<nb, SCAN_B, 0, stream>>>(cnt, offs, bsums, dinv, N);
    scan2_kernel<<<1, SCAN_B, 0, stream>>>(bsums, nb);
    scan3_kernel<<<(N + 1 + 255) / 256, 256, 0, stream>>>(offs, bsums, cursor, N, E);
    place_kernel<<<2048, 256, 0, stream>>>(ei, E, cursor, edges, N);

    // ---- seed: xd = dinv.*x, z = w[order]*xd (slab layout) ----
    const int nch = (N + 255) / 256;
    conv_kernel<<<nch * 8, 256, 0, stream>>>(x, dinv, xd, zA, wts, order, N);

    // ---- 10 Horner rounds on z: s = (A+I)z; z' = dinv^2 s + wj xd ----
    // block = 256 threads = 4 waves = 32 nodes; grid = ceil(N/32) x 8 slabs
    const int nodechunks = (N + 31) / 32;
    const unsigned* zin = zA;
    unsigned* zout = zB;
    for (int j = order - 1; j >= 0; --j) {
        int last = (j == 0);
        prop_kernel<<<nodechunks * 8, 256, 0, stream>>>(zin, zout, out, xd, x,
                                                        dinv, offs, edges, wts,
                                                        j, last, N, E);
        zin = zout;
        zout = (zout == zA) ? zB : zA;
    }
}

// Round 14
// 1216.824 us; speedup vs baseline: 3.0668x; 1.4406x over previous
//
#include <hip/hip_runtime.h>
#include <hip/hip_fp16.h>

// GPRPropagation: out = sum_k w_k * (D^-1/2 (A+I) D^-1/2)^k x, k=0..ORDER
// N=100000, F=128, E=1600000, ORDER=10.
//
// Confirmed (R10-R12): feature-sliced slabs [g][node][16 fp16] with
// blockIdx&7 XCD affinity make random gathers L2-resident (FETCH ~59MB =
// compulsory floor; WRITE 25MB). R12 codegen-strangled (VGPR=8): divergent
// load bodies + volatile asm serialized. R13 fixed that via arithmetic
// predication + unroll-4 but broke numerics: split single-output asm with
// "+v" tie made %N numbering ambiguous (clang counts tied inputs), so the
// hi-half FMA read the wrong register. R14: NAMED asm operands (%[ax],
// %[raw]) in the two-output form — unambiguous — still non-volatile.

#define F 128
#define SCAN_B 256

__global__ void count_kernel(const int* __restrict__ ei, int E,
                             int* __restrict__ cnt) {
    int e = blockIdx.x * blockDim.x + threadIdx.x;
    if (e < E) {
        int c = ei[(size_t)E + e];   // col = destination
        atomicAdd(&cnt[c], 1);
    }
}

// scan1 + dinv fused
__global__ void scan1_kernel(const int* __restrict__ cnt, int* __restrict__ offs,
                             int* __restrict__ bsums, float* __restrict__ dinv,
                             int N) {
    __shared__ int sm[SCAN_B];
    int i = blockIdx.x * SCAN_B + threadIdx.x;
    int v = (i < N) ? cnt[i] : 0;
    if (i < N) dinv[i] = rsqrtf((float)(v + 1));  // + self loop
    sm[threadIdx.x] = v;
    __syncthreads();
    for (int d = 1; d < SCAN_B; d <<= 1) {
        int t = (threadIdx.x >= d) ? sm[threadIdx.x - d] : 0;
        __syncthreads();
        sm[threadIdx.x] += t;
        __syncthreads();
    }
    if (i < N) offs[i] = sm[threadIdx.x] - v;
    if (threadIdx.x == SCAN_B - 1) bsums[blockIdx.x] = sm[SCAN_B - 1];
}

__global__ void scan2_kernel(int* __restrict__ bsums, int nb) {
    __shared__ int sm[SCAN_B];
    __shared__ int carry;
    if (threadIdx.x == 0) carry = 0;
    __syncthreads();
    for (int base = 0; base < nb; base += SCAN_B) {
        int i = base + threadIdx.x;
        int v = (i < nb) ? bsums[i] : 0;
        sm[threadIdx.x] = v;
        __syncthreads();
        for (int d = 1; d < SCAN_B; d <<= 1) {
            int t = (threadIdx.x >= d) ? sm[threadIdx.x - d] : 0;
            __syncthreads();
            sm[threadIdx.x] += t;
            __syncthreads();
        }
        if (i < nb) bsums[i] = sm[threadIdx.x] - v + carry;
        __syncthreads();
        if (threadIdx.x == 0) carry += sm[SCAN_B - 1];
        __syncthreads();
    }
}

__global__ void scan3_kernel(int* __restrict__ offs, const int* __restrict__ bsums,
                             int* __restrict__ cursor, int N, int E) {
    int i = blockIdx.x * blockDim.x + threadIdx.x;
    if (i < N) {
        int o = offs[i] + bsums[i / SCAN_B];
        offs[i] = o;
        cursor[i] = o;
    }
    if (i == N) offs[N] = E;
}

// 8-group rescan place (R6): group g handles dst range [N*g/8, N*(g+1)/8);
// its CSR slice is contiguous -> XCD-local atomics + full-line writeback.
__global__ void place_kernel(const int* __restrict__ ei, int E,
                             int* __restrict__ cursor, int* __restrict__ edges,
                             int N) {
    const int g = blockIdx.x & 7;
    const int b = blockIdx.x >> 3;
    const int nb = gridDim.x >> 3;
    const int lo = (int)((long long)N * g / 8);
    const int hi = (int)((long long)N * (g + 1) / 8);
    const int stride = nb * blockDim.x;
    for (int e = b * blockDim.x + threadIdx.x; e < E; e += stride) {
        int c = ei[(size_t)E + e];
        if (c < lo || c >= hi) continue;
        int pos = atomicAdd(&cursor[c], 1);
        edges[pos] = ei[e];
    }
}

__device__ __forceinline__ unsigned pk(float a, float b) {
    __half2 h = __floats2half2_rn(a, b);
    return *(unsigned*)&h;
}

// acc.x += f16_lo(raw); acc.y += f16_hi(raw)  (fp32 FMA, no cvt; named ops)
__device__ __forceinline__ void accmix(float& ax, float& ay, unsigned raw) {
    asm("v_fma_mix_f32 %[ax], 1.0, %[raw], %[ax] op_sel:[0,0,0] op_sel_hi:[0,1,0]\n\t"
        "v_fma_mix_f32 %[ay], 1.0, %[raw], %[ay] op_sel:[0,1,0] op_sel_hi:[0,1,0]"
        : [ax] "+v"(ax), [ay] "+v"(ay)
        : [raw] "v"(raw));
}

// acc.x += w * f16_lo(raw); acc.y += w * f16_hi(raw)
__device__ __forceinline__ void fmamix2(float& ax, float& ay, float w,
                                        unsigned raw) {
    asm("v_fma_mix_f32 %[ax], %[w], %[raw], %[ax] op_sel:[0,0,0] op_sel_hi:[0,1,0]\n\t"
        "v_fma_mix_f32 %[ay], %[w], %[raw], %[ay] op_sel:[0,1,0] op_sel_hi:[0,1,0]"
        : [ax] "+v"(ax), [ay] "+v"(ay)
        : [w] "v"(w), [raw] "v"(raw));
}

// Seed: xd = fp16(dinv.*x), z = fp16(w[order]*dinv.*x), slab layout
// [g][node][8 u32 (=16 halfs)]. g = blockIdx&7.
__global__ __launch_bounds__(256) void conv_kernel(
    const float* __restrict__ x, const float* __restrict__ dinv,
    unsigned* __restrict__ xd, unsigned* __restrict__ z,
    const float* __restrict__ wts, int order, int N) {
    const int g = blockIdx.x & 7;
    const int c = (blockIdx.x >> 3) * blockDim.x + threadIdx.x;
    if (c >= N) return;
    const float dc = dinv[c];
    const float wl = wts[order] * dc;
    const float2* xr = (const float2*)(x + (size_t)c * F + g * 16);
    size_t off = ((size_t)g * N + c) * 8;
#pragma unroll
    for (int k = 0; k < 8; ++k) {
        float2 v = xr[k];
        xd[off + k] = pk(dc * v.x, dc * v.y);
        z[off + k] = pk(wl * v.x, wl * v.y);
    }
}

// Wave = 8 consecutive dst nodes (slot = lane>>3) x 8 feature pairs
// (fl = lane&7). Max-degree uniform loop, ARITHMETIC predication:
// clamped edge index (always in-bounds), select loaded value to 0 for
// it >= deg. Unroll x4 -> 4 independent edge->z chains, no branches.
__global__ __launch_bounds__(256) void prop_kernel(
    const unsigned* __restrict__ z_old, unsigned* __restrict__ z_new,
    float* __restrict__ out, const unsigned* __restrict__ xd,
    const float* __restrict__ x, const float* __restrict__ dinv,
    const int* __restrict__ offs, const int* __restrict__ edges,
    const float* __restrict__ wts, int j, int last, int N) {
    const int g = blockIdx.x & 7;
    const int lane = threadIdx.x & 63;
    const int slot = lane >> 3;
    const int fl = lane & 7;
    const int c = (((blockIdx.x >> 3) << 2) + (threadIdx.x >> 6)) * 8 + slot;
    const bool act = (c < N);
    const int cc = act ? c : 0;
    const unsigned* zs = z_old + (size_t)g * N * 8;  // this XCD's 3.2MB slab

    const int beg = offs[cc];
    const int deg = offs[cc + 1] - beg;

    float ax = 0.0f, ay = 0.0f;
    {
        unsigned zc = zs[(size_t)cc * 8 + fl];
        if (!act) zc = 0u;
        accmix(ax, ay, zc);  // self loop
    }

    // wave-uniform trip count = max degree over the 8 slots (lane bits 3..5)
    int m = act ? deg : 0;
    m = max(m, __shfl_xor(m, 8));
    m = max(m, __shfl_xor(m, 16));
    m = max(m, __shfl_xor(m, 32));

    const int degm1 = max(deg - 1, 0);
    int it = 0;
    for (; it + 4 <= m; it += 4) {
        int i0 = beg + min(it + 0, degm1);
        int i1 = beg + min(it + 1, degm1);
        int i2 = beg + min(it + 2, degm1);
        int i3 = beg + min(it + 3, degm1);
        int s0 = edges[i0];
        int s1 = edges[i1];
        int s2 = edges[i2];
        int s3 = edges[i3];
        s0 = (it + 0 < deg) ? s0 : 0;
        s1 = (it + 1 < deg) ? s1 : 0;
        s2 = (it + 2 < deg) ? s2 : 0;
        s3 = (it + 3 < deg) ? s3 : 0;
        unsigned z0 = zs[(size_t)s0 * 8 + fl];
        unsigned z1 = zs[(size_t)s1 * 8 + fl];
        unsigned z2 = zs[(size_t)s2 * 8 + fl];
        unsigned z3 = zs[(size_t)s3 * 8 + fl];
        z0 = (it + 0 < deg) ? z0 : 0u;
        z1 = (it + 1 < deg) ? z1 : 0u;
        z2 = (it + 2 < deg) ? z2 : 0u;
        z3 = (it + 3 < deg) ? z3 : 0u;
        accmix(ax, ay, z0);
        accmix(ax, ay, z1);
        accmix(ax, ay, z2);
        accmix(ax, ay, z3);
    }
    for (; it < m; ++it) {
        int i0 = beg + min(it, degm1);
        int s0 = edges[i0];
        s0 = (it < deg) ? s0 : 0;
        unsigned z0 = zs[(size_t)s0 * 8 + fl];
        z0 = (it < deg) ? z0 : 0u;
        accmix(ax, ay, z0);
    }

    if (act) {
        const float dc = dinv[c];
        if (last) {
            const float w0 = wts[0];
            const float2 xv = ((const float2*)(x + (size_t)c * F + g * 16))[fl];
            float* orow = out + (size_t)c * F + g * 16 + fl * 2;
            __builtin_nontemporal_store(fmaf(dc, ax, w0 * xv.x), orow);
            __builtin_nontemporal_store(fmaf(dc, ay, w0 * xv.y), orow + 1);
        } else {
            const float dc2 = dc * dc;
            const float wj = wts[j];
            size_t off = ((size_t)g * N + c) * 8 + fl;
            unsigned xr = __builtin_nontemporal_load(&xd[off]);
            ax *= dc2;
            ay *= dc2;
            fmamix2(ax, ay, wj, xr);
            __builtin_nontemporal_store(pk(ax, ay), &z_new[off]);
        }
    }
}

extern "C" void kernel_launch(void* const* d_in, const int* in_sizes, int n_in,
                              void* d_out, int out_size, void* d_ws, size_t ws_size,
                              hipStream_t stream) {
    const float* x = (const float*)d_in[0];
    const int* ei = (const int*)d_in[1];
    const float* wts = (const float*)d_in[2];
    float* out = (float*)d_out;

    const int NF = in_sizes[0];
    const int N = NF / F;              // 100000
    const int E = in_sizes[1] / 2;     // 1600000
    const int order = in_sizes[2] - 1; // 10

    char* p = (char*)d_ws;
    auto carve = [&](size_t bytes) {
        void* q = (void*)p;
        p += (bytes + 255) & ~(size_t)255;
        return q;
    };
    int nb = (N + SCAN_B - 1) / SCAN_B;
    int*      cnt   = (int*)carve(sizeof(int) * (size_t)N);  // reused as cursor
    int*      offs  = (int*)carve(sizeof(int) * (size_t)(N + 1));
    int*      bsums = (int*)carve(sizeof(int) * (size_t)nb);
    float*    dinv  = (float*)carve(sizeof(float) * (size_t)N);
    int*      edges = (int*)carve(4ull * (size_t)E);
    unsigned* xd    = (unsigned*)carve(32ull * (size_t)N * 8);
    unsigned* zA    = (unsigned*)carve(32ull * (size_t)N * 8);
    unsigned* zB    = (unsigned*)carve(32ull * (size_t)N * 8);
    int*      cursor = cnt;  // cnt dead after scan1
    (void)ws_size;

    // ---- CSR build + normalization ----
    hipMemsetAsync(cnt, 0, sizeof(int) * (size_t)N, stream);
    count_kernel<<<(E + 255) / 256, 256, 0, stream>>>(ei, E, cnt);
    scan1_kernel<<<nb, SCAN_B, 0, stream>>>(cnt, offs, bsums, dinv, N);
    scan2_kernel<<<1, SCAN_B, 0, stream>>>(bsums, nb);
    scan3_kernel<<<(N + 1 + 255) / 256, 256, 0, stream>>>(offs, bsums, cursor, N, E);
    place_kernel<<<2048, 256, 0, stream>>>(ei, E, cursor, edges, N);

    // ---- seed: xd = dinv.*x, z = w[order]*xd (slab layout) ----
    const int nch = (N + 255) / 256;
    conv_kernel<<<nch * 8, 256, 0, stream>>>(x, dinv, xd, zA, wts, order, N);

    // ---- 10 Horner rounds on z: s = (A+I)z; z' = dinv^2 s + wj xd ----
    // block = 256 threads = 4 waves = 32 nodes; grid = ceil(N/32) x 8 slabs
    const int nodechunks = (N + 31) / 32;
    const unsigned* zin = zA;
    unsigned* zout = zB;
    for (int j = order - 1; j >= 0; --j) {
        int last = (j == 0);
        prop_kernel<<<nodechunks * 8, 256, 0, stream>>>(zin, zout, out, xd, x,
                                                        dinv, offs, edges, wts,
                                                        j, last, N);
        zin = zout;
        zout = (zout == zA) ? zB : zA;
    }
}